// Round 9
// baseline (7522.031 us; speedup 1.0000x reference)
//
#include <hip/hip_runtime.h>
#include <cmath>

typedef __attribute__((ext_vector_type(8))) short short8;
typedef __attribute__((ext_vector_type(4))) float f32x4;
typedef unsigned long long u64;
typedef unsigned int u32;

#define RS 2208   // A row stride in bf16 (2176 data + 32 pad -> rows offset by 16 banks)
#define AG __ATOMIC_RELAXED, __HIP_MEMORY_SCOPE_AGENT

__device__ __forceinline__ unsigned short f2bf(float x){
  u32 u = __float_as_uint(x);
  u32 r = u + 0x7FFFu + ((u >> 16) & 1u);   // round-to-nearest-even bf16
  return (unsigned short)(r >> 16);
}

__device__ __forceinline__ float tanh_fast(float x){
  float xc = fminf(fmaxf(x, -10.f), 10.f);   // tanh(10)=1-4e-9; also keeps exp finite
  float e = __expf(2.f * xc);
  return (e - 1.f) / (e + 1.f);
}

// Pre-swizzle [w_res ; w_in] (K=2176 x 2048 cols) into bf16 MFMA B-fragment order.
// Layout: [gcg 0..127][ks 0..1][f 0..33][lane 0..63][j 0..7]:
//   k = ks*1088 + f*32 + (l>>4)*8 + j, col = gcg*16 + (l&15).
__global__ void bswz_kernel(const float* __restrict__ wres,
                            const float* __restrict__ win,
                            unsigned short* __restrict__ B){
  int tid = blockIdx.x * 256 + threadIdx.x;
  int l   = tid & 63;
  int cf  = tid >> 6;          // (gcg*2+ks)*34 + f
  int f   = cf % 34;
  int gk  = cf / 34;
  int ks  = gk & 1;
  int gcg = gk >> 1;
  int col = (gcg << 4) + (l & 15);
  int k0  = ks * 1088 + (f << 5) + ((l >> 4) << 3);
  short8 vv;
  #pragma unroll
  for (int j = 0; j < 8; ++j){
    int k = k0 + j;
    float v = (k < 2048) ? wres[(size_t)k * 2048 + col]
                         : win[(size_t)(k - 2048) * 2048 + col];
    vv[j] = (short)f2bf(v);
  }
  *((short8*)(B + (size_t)tid * 8)) = vv;
}

// out[b][t][0:128] = inputs  (concat head).  262144 float4s = 1024 blocks x 256.
__global__ void copy_in_kernel(const float* __restrict__ in, float* __restrict__ out){
  int i = blockIdx.x * 256 + threadIdx.x;
  int bt = i >> 5;
  int d4 = i & 31;
  float4 v = ((const float4*)in)[i];
  ((float4*)(out + (size_t)bt * 2176))[d4] = v;
}

// ex layout (u64): [0,8192)   data: [parity 2][row 8][512 entries] (parity0=0 -> s_0)
//                  [8192,12288) tags: [group 4][wave 128][8]  (64B-spaced monotonic u64)
// All zeroed: tag==0 < need, and t=0 reads parity-0 zeros = s_0 directly.
__global__ void exinit_kernel(u64* __restrict__ ex){
  int i = blockIdx.x * 256 + threadIdx.x;   // 48*256 = 12288 entries
  ex[i] = 0ULL;
}

// Persistent ESN scan: 128 blocks x 512 threads = 4 row-pairs x 32 col-blocks of 64 cols.
// r9 signaling redesign (flood fix): per-producer-WAVE tag lines + one-shot data reads.
//  - producer wave (ks==0, cg): 8 relaxed atomic data stores, then lane0 RELEASE-stores
//    tag[cb*4+cg] = t+1 (the release's vmcnt(0) drains the wave's data stores first,
//    so tag-visible => data-visible at the coherence point).
//  - consumer: only 128 threads poll (thread w spins on tag[w] >= t, its own 64B line),
//    then one-shot reads that producer wave's 64B (2 rows x 4 u64) and stages to LDS.
//  Poll request flood drops ~16x (512 pollers re-polling 16B -> 128 pollers on 1 line);
//  data moves once. Monotonic tags: no ABA, no re-init, deadlock-free.
__global__ void __launch_bounds__(512, 2) esn_persist(
    const float* __restrict__ inputs,
    const float* __restrict__ b_in,
    const unsigned short* __restrict__ Bsw,
    u64* __restrict__ ex,
    float* __restrict__ out)
{
  __shared__ __align__(16) unsigned short As[2 * RS];  // [row 0/1][k: 2048 state + 128 x_t + pad]
  __shared__ float red[2][4][16][2];                   // [parity][cg][m16][row]

  const int tid = threadIdx.x;
  const int blk = blockIdx.x;      // 0..127
  const int r0  = (blk >> 5) << 1; // batch rows {r0, r0+1}
  const int cb  = blk & 31;        // column block: cols [cb*64, cb*64+64)
  const int wv  = tid >> 6;        // 0..7
  const int l   = tid & 63;
  const int m16 = l & 15;
  const int q   = l >> 4;
  const int cg  = wv >> 1;         // col-group 0..3 (16 cols each)
  const int ks  = wv & 1;          // K-split 0/1 (K=1088 each)
  const int gcg = (cb << 2) + cg;  // global col-group 0..127
  const int colw0 = gcg << 4;

  // B fragments in registers for the whole scan (34 per wave = 136 VGPRs)
  short8 Bf[34];
  {
    const short8* bp = (const short8*)Bsw + (size_t)((gcg << 1) + ks) * 34 * 64 + l;
    #pragma unroll
    for (int f = 0; f < 34; ++f) Bf[f] = bp[f * 64];
  }
  const float bias = b_in[colw0 + m16];
  float s0 = 0.f, s1 = 0.f;        // fp32 leak-path state (ks==0, lanes<16)

  const float* xr0 = inputs + (size_t)r0 * 1024 * 128;
  u64* tags = ex + 8192 + ((size_t)(r0 >> 1) * 1024);   // this group's 128 tag slots

  // register x-prefetch (r6-proven): overlaps the global x load with the wait
  float4 xv;
  if (tid < 64) xv = ((const float4*)(xr0 + (size_t)(tid >> 5) * 1024 * 128))[tid & 31];

  for (int t = 0; t < 1024; ++t){
    // ---- stage x_t from regs: 64 threads, packed 8B LDS writes; prefetch x_{t+1} ----
    if (tid < 64){
      const int row = tid >> 5;
      const int c   = tid & 31;
      u64 pk = (u64)f2bf(xv.x) | ((u64)f2bf(xv.y) << 16)
             | ((u64)f2bf(xv.z) << 32) | ((u64)f2bf(xv.w) << 48);
      *((u64*)&As[row * RS + 2048 + (c << 2)]) = pk;
      if (t < 1023)
        xv = ((const float4*)(xr0 + ((size_t)row * 1024 + t + 1) * 128))[c];
    }
    // ---- tag wait + one-shot data read: thread w<128 handles producer wave w ----
    if (tid < 128){
      if (t){
        const u64 need = (u64)t;
        u64 v = __hip_atomic_load(&tags[tid << 3], AG);
        while (v < need) v = __hip_atomic_load(&tags[tid << 3], AG);
      }
      const u64* srcb = ex + ((size_t)(t & 1) * 8 + r0) * 512;
      u64 d0 = __hip_atomic_load(&srcb[(tid << 2) + 0], AG);
      u64 d1 = __hip_atomic_load(&srcb[(tid << 2) + 1], AG);
      u64 d2 = __hip_atomic_load(&srcb[(tid << 2) + 2], AG);
      u64 d3 = __hip_atomic_load(&srcb[(tid << 2) + 3], AG);
      u64 e0 = __hip_atomic_load(&srcb[512 + (tid << 2) + 0], AG);
      u64 e1 = __hip_atomic_load(&srcb[512 + (tid << 2) + 1], AG);
      u64 e2 = __hip_atomic_load(&srcb[512 + (tid << 2) + 2], AG);
      u64 e3 = __hip_atomic_load(&srcb[512 + (tid << 2) + 3], AG);
      u64* dst0 = (u64*)&As[tid << 4];         // entry idx tid*4 -> short idx tid*16
      dst0[0] = d0; dst0[1] = d1; dst0[2] = d2; dst0[3] = d3;
      u64* dst1 = (u64*)&As[RS + (tid << 4)];
      dst1[0] = e0; dst1[1] = e1; dst1[2] = e2; dst1[3] = e3;
    }
    __syncthreads();

    // ---- MFMA: M=2, K=1088 per wave, 34 x 16x16x32, 2 interleaved acc chains.
    // Unconditional A read, row = m16&1: 8 lanes/address -> free LDS broadcast;
    // lanes m16>=2 feed garbage into D rows 2..15 which are never read.
    f32x4 acc0 = {0.f,0.f,0.f,0.f}, acc1 = {0.f,0.f,0.f,0.f};
    {
      const unsigned short* Ab = &As[(m16 & 1) * RS + ks * 1088 + (q << 3)];
      #pragma unroll
      for (int f = 0; f < 34; f += 2){
        short8 a0 = *((const short8*)(Ab + (f << 5)));
        short8 a1 = *((const short8*)(Ab + ((f + 1) << 5)));
        acc0 = __builtin_amdgcn_mfma_f32_16x16x32_bf16(a0, Bf[f],     acc0, 0, 0, 0);
        acc1 = __builtin_amdgcn_mfma_f32_16x16x32_bf16(a1, Bf[f + 1], acc1, 0, 0, 0);
      }
    }
    // C/D: col=l&15, row=q*4+reg -> batch rows 0,1 live in lanes 0..15, regs 0,1
    float p0 = acc0[0] + acc1[0];
    float p1 = acc0[1] + acc1[1];
    if (ks == 1 && l < 16){
      red[t & 1][cg][m16][0] = p0;
      red[t & 1][cg][m16][1] = p1;
    }
    __syncthreads();

    // ---- ks==0 lanes<16: reduce, tanh, leak, publish data, release tag, out ----
    if (ks == 0 && l < 16){
      p0 += red[t & 1][cg][m16][0];
      p1 += red[t & 1][cg][m16][1];
      float nv0 = 0.5f * s0 + 0.5f * tanh_fast(p0 + bias);
      float nv1 = 0.5f * s1 + 0.5f * tanh_fast(p1 + bias);
      s0 = nv0; s1 = nv1;
      u32 b0 = (u32)f2bf(nv0);                     // full precision: no tag bit in data
      u32 b1 = (u32)f2bf(nv1);
      // pack 4 lanes' cols into one u64 (valid on lanes m16%4==0)
      u32 pr0 = b0 | (((u32)__shfl_xor((int)b0, 1)) << 16);
      u32 pr1 = b1 | (((u32)__shfl_xor((int)b1, 1)) << 16);
      u64 ev0 = (u64)pr0 | ((u64)(u32)__shfl_xor((int)pr0, 2) << 32);
      u64 ev1 = (u64)pr1 | ((u64)(u32)__shfl_xor((int)pr1, 2) << 32);
      if ((m16 & 3) == 0){
        u64* exw = ex + ((size_t)((t + 1) & 1) * 8 + r0) * 512;
        const int p = (colw0 + m16) >> 2;
        __hip_atomic_store(&exw[p],       ev0, AG);
        __hip_atomic_store(&exw[512 + p], ev1, AG);
      }
      if (m16 == 0){
        // RELEASE: drains this wave's 8 data stores before the tag lands
        __hip_atomic_store(&tags[((cb << 2) + cg) << 3], (u64)(t + 1),
                           __ATOMIC_RELEASE, __HIP_MEMORY_SCOPE_AGENT);
      }
      const int u = colw0 + m16;
      float pw0 = (u & 1) ? nv0 : nv0 * nv0;       // PowerIndex: even u squared
      float pw1 = (u & 1) ? nv1 : nv1 * nv1;
      out[((size_t)r0 * 1024 + t) * 2176 + 128 + u] = pw0;
      out[((size_t)(r0 + 1) * 1024 + t) * 2176 + 128 + u] = pw1;
    }
    // no third barrier: As reads complete before barrier 2; red is parity-double-buffered
  }
}

extern "C" void kernel_launch(void* const* d_in, const int* in_sizes, int n_in,
                              void* d_out, int out_size, void* d_ws, size_t ws_size,
                              hipStream_t stream){
  const float* inputs = (const float*)d_in[0];   // [8,1024,128]
  const float* w_in   = (const float*)d_in[1];   // [128,2048]
  const float* b_in   = (const float*)d_in[2];   // [2048]
  const float* w_res  = (const float*)d_in[3];   // [2048,2048]
  float* out = (float*)d_out;

  u64* ex = (u64*)d_ws;                                         // 12288 u64 = 98304 B (data+tags)
  unsigned short* Bsw = (unsigned short*)((char*)d_ws + 98304); // 8,912,896 B swizzled weights

  exinit_kernel<<<48, 256, 0, stream>>>(ex);
  bswz_kernel<<<2176, 256, 0, stream>>>(w_res, w_in, Bsw);
  copy_in_kernel<<<1024, 256, 0, stream>>>(inputs, out);
  esn_persist<<<128, 512, 0, stream>>>(inputs, b_in, Bsw, ex, out);
}

// Round 10
// 4072.502 us; speedup vs baseline: 1.8470x; 1.8470x over previous
//
#include <hip/hip_runtime.h>
#include <cmath>

typedef __attribute__((ext_vector_type(8))) short short8;
typedef __attribute__((ext_vector_type(4))) float f32x4;
typedef unsigned long long u64;
typedef unsigned int u32;

#define AG __ATOMIC_RELAXED, __HIP_MEMORY_SCOPE_AGENT

__device__ __forceinline__ unsigned short f2bf(float x){
  u32 u = __float_as_uint(x);
  u32 r = u + 0x7FFFu + ((u >> 16) & 1u);   // round-to-nearest-even bf16
  return (unsigned short)(r >> 16);
}

__device__ __forceinline__ float tanh_fast(float x){
  float xc = fminf(fmaxf(x, -10.f), 10.f);   // tanh(10)=1-4e-9; also keeps exp finite
  float e = __expf(2.f * xc);
  return (e - 1.f) / (e + 1.f);
}

// Pre-swizzle [w_res ; w_in] (K=2176 x 2048 cols) into bf16 MFMA B-fragment order.
// Layout: [gcg 0..127][ks 0..1][f 0..33][lane 0..63][j 0..7]:
//   k = ks*1088 + f*32 + (l>>4)*8 + j, col = gcg*16 + (l&15).
__global__ void bswz_kernel(const float* __restrict__ wres,
                            const float* __restrict__ win,
                            unsigned short* __restrict__ B){
  int tid = blockIdx.x * 256 + threadIdx.x;
  int l   = tid & 63;
  int cf  = tid >> 6;          // (gcg*2+ks)*34 + f
  int f   = cf % 34;
  int gk  = cf / 34;
  int ks  = gk & 1;
  int gcg = gk >> 1;
  int col = (gcg << 4) + (l & 15);
  int k0  = ks * 1088 + (f << 5) + ((l >> 4) << 3);
  short8 vv;
  #pragma unroll
  for (int j = 0; j < 8; ++j){
    int k = k0 + j;
    float v = (k < 2048) ? wres[(size_t)k * 2048 + col]
                         : win[(size_t)(k - 2048) * 2048 + col];
    vv[j] = (short)f2bf(v);
  }
  *((short8*)(B + (size_t)tid * 8)) = vv;
}

// out[b][t][0:128] = inputs  (concat head).  262144 float4s = 1024 blocks x 256.
__global__ void copy_in_kernel(const float* __restrict__ in, float* __restrict__ out){
  int i = blockIdx.x * 256 + threadIdx.x;
  int bt = i >> 5;
  int d4 = i & 31;
  float4 v = ((const float4*)in)[i];
  ((float4*)(out + (size_t)bt * 2176))[d4] = v;
}

// Exchange init: ex[2][8][512] u64.  Parity 0 = 0 (tag-bit 0, s_0 = 0 -> valid for t=0).
// Parity 1 = all-bf16-LSB=1 (tag-bit 1): t=1 wants bit 0 -> init rejected until real data.
__global__ void exinit_kernel(u64* __restrict__ ex){
  int i = blockIdx.x * 256 + threadIdx.x;   // 8192 entries
  ex[i] = (i < 4096) ? 0ULL : 0x0001000100010001ULL;
}

// Persistent ESN scan: 128 blocks x 512 threads = 4 row-pairs x 32 col-blocks of 64 cols.
// r10: WAVE-AUTONOMOUS SLICES. Each wave polls exactly the exchange entries its own
// MFMA consumes (its K-half x both rows, tag-in-data protocol unchanged) into a
// wave-private LDS slice, then goes straight to MFMA -- no barrier-1, no waiting on
// the globally-slowest entry. One barrier/step (the ks-reduce). ks=1 waves stage x_t
// from their own prefetch registers (k_local 960..1088 of their slice).
__global__ void __launch_bounds__(512, 2) esn_persist(
    const float* __restrict__ inputs,
    const float* __restrict__ b_in,
    const unsigned short* __restrict__ Bsw,
    u64* __restrict__ ex,          // ex[parity 2][row 8][512 entries]
    float* __restrict__ out)
{
  __shared__ __align__(16) unsigned short As[8][2][1104]; // [wave][row][K-half 1088 + pad]
  __shared__ float red[2][4][16][2];                      // [parity][cg][m16][row]

  const int tid = threadIdx.x;
  const int blk = blockIdx.x;      // 0..127
  const int r0  = (blk >> 5) << 1; // batch rows {r0, r0+1}
  const int cb  = blk & 31;        // column block: cols [cb*64, cb*64+64)
  const int wv  = tid >> 6;        // 0..7
  const int l   = tid & 63;
  const int m16 = l & 15;
  const int q   = l >> 4;
  const int cg  = wv >> 1;         // col-group 0..3 (16 cols each)
  const int ks  = wv & 1;          // K-split 0/1 (K=1088 each)
  const int gcg = (cb << 2) + cg;  // global col-group 0..127
  const int colw0 = gcg << 4;

  // B fragments in registers for the whole scan (34 per wave)
  short8 Bf[34];
  {
    const short8* bp = (const short8*)Bsw + (size_t)((gcg << 1) + ks) * 34 * 64 + l;
    #pragma unroll
    for (int f = 0; f < 34; ++f) Bf[f] = bp[f * 64];
  }
  const float bias = b_in[colw0 + m16];
  float s0 = 0.f, s1 = 0.f;        // fp32 leak-path state (ks==0, lanes<16)

  const float* xr0 = inputs + (size_t)r0 * 1024 * 128;
  const u64 M = 0x0001000100010001ULL;

  // Per-lane poll-entry list (u64 indices within one row's 512-entry block).
  // ks=0 covers entries [0,272) (state cols 0..1088); ks=1 covers [272,512)
  // (state cols 1088..2048). Slots 0..4 = row0, 5..9 = row1; gated by pend0.
  int eidx[5];
  u32 pend0;
  if (ks == 0){
    eidx[0] = l; eidx[1] = l + 64; eidx[2] = l + 128; eidx[3] = l + 192;
    eidx[4] = (l < 16) ? l + 256 : 0;
    pend0 = (l < 16) ? 0x3FFu : 0x1EFu;        // bits {4,9} only for l<16
  } else {
    eidx[0] = 272 + l; eidx[1] = 336 + l; eidx[2] = 400 + l;
    eidx[3] = (l < 48) ? 464 + l : 0;
    eidx[4] = 0;
    pend0 = (l < 48) ? 0x1EFu : 0x0E7u;        // bits {3,8} only for l<48; {4,9} never
  }

  // x prefetch: ks=1 waves stage x themselves (k_local 960..1088)
  const int xrow = l >> 5, xc = l & 31;
  float4 xv;
  if (ks == 1) xv = ((const float4*)(xr0 + (size_t)xrow * 1024 * 128))[xc];

  for (int t = 0; t < 1024; ++t){
    // ---- stage x_t from regs (ks=1 waves, own slice); prefetch x_{t+1} ----
    if (ks == 1){
      u64 pk = (u64)f2bf(xv.x) | ((u64)f2bf(xv.y) << 16)
             | ((u64)f2bf(xv.z) << 32) | ((u64)f2bf(xv.w) << 48);
      *((u64*)&As[wv][xrow][960 + (xc << 2)]) = pk;
      if (t < 1023)
        xv = ((const float4*)(xr0 + ((size_t)xrow * 1024 + t + 1) * 128))[xc];
    }
    // ---- poll own slice (tag-in-data, pend-masked, all loads batched in flight) ----
    {
      u64* srcb = ex + ((size_t)(t & 1) * 8 + r0) * 512;
      const u64 want = ((t >> 1) & 1) ? M : 0ULL;
      u64 vb[10];
      u32 pend = pend0;
      #pragma unroll
      for (int i = 0; i < 10; ++i)
        if (pend & (1u << i))
          vb[i] = __hip_atomic_load(&srcb[(i >= 5 ? 512 : 0) + eidx[i % 5]], AG);
      for (;;){
        u32 np = 0;
        #pragma unroll
        for (int i = 0; i < 10; ++i){
          if (pend & (1u << i)){
            if ((vb[i] & M) == want){
              const int e   = eidx[i % 5];
              const int row = (i >= 5);
              const int kl  = (ks == 0) ? (e << 2) : ((e << 2) - 1088);
              *((u64*)&As[wv][row][kl]) = vb[i];
            } else np |= (1u << i);
          }
        }
        pend = np;
        if (!pend) break;
        #pragma unroll
        for (int i = 0; i < 10; ++i)
          if (pend & (1u << i))
            vb[i] = __hip_atomic_load(&srcb[(i >= 5 ? 512 : 0) + eidx[i % 5]], AG);
      }
    }
    // NO barrier: slice is wave-private; in-wave ds ordering (lgkmcnt) suffices.

    // ---- MFMA: M=2, K=1088 per wave, 34 x 16x16x32, 2 interleaved acc chains.
    // Unconditional A read, row = m16&1: 8 lanes/address -> LDS broadcast;
    // lanes m16>=2 feed garbage into D rows 2..15 which are never read.
    f32x4 acc0 = {0.f,0.f,0.f,0.f}, acc1 = {0.f,0.f,0.f,0.f};
    {
      const unsigned short* Ab = &As[wv][m16 & 1][q << 3];
      #pragma unroll
      for (int f = 0; f < 34; f += 2){
        short8 a0 = *((const short8*)(Ab + (f << 5)));
        short8 a1 = *((const short8*)(Ab + ((f + 1) << 5)));
        acc0 = __builtin_amdgcn_mfma_f32_16x16x32_bf16(a0, Bf[f],     acc0, 0, 0, 0);
        acc1 = __builtin_amdgcn_mfma_f32_16x16x32_bf16(a1, Bf[f + 1], acc1, 0, 0, 0);
      }
    }
    // C/D: col=l&15, row=q*4+reg -> batch rows 0,1 live in lanes 0..15, regs 0,1
    float p0 = acc0[0] + acc1[0];
    float p1 = acc0[1] + acc1[1];
    if (ks == 1 && l < 16){
      red[t & 1][cg][m16][0] = p0;
      red[t & 1][cg][m16][1] = p1;
    }
    __syncthreads();   // the ONLY barrier per step

    // ---- ks==0 lanes<16: reduce, tanh, leak, publish FIRST, then out stores ----
    if (ks == 0 && l < 16){
      p0 += red[t & 1][cg][m16][0];
      p1 += red[t & 1][cg][m16][1];
      float nv0 = 0.5f * s0 + 0.5f * tanh_fast(p0 + bias);
      float nv1 = 0.5f * s1 + 0.5f * tanh_fast(p1 + bias);
      s0 = nv0; s1 = nv1;
      const u32 bit = (u32)(((t + 1) >> 1) & 1);
      u32 b0 = ((u32)f2bf(nv0) & 0xFFFEu) | bit;   // tag-bit in bf16 LSB
      u32 b1 = ((u32)f2bf(nv1) & 0xFFFEu) | bit;
      // pack 4 lanes' cols into one u64 (valid on lanes m16%4==0)
      u32 pr0 = b0 | (((u32)__shfl_xor((int)b0, 1)) << 16);
      u32 pr1 = b1 | (((u32)__shfl_xor((int)b1, 1)) << 16);
      u64 e0 = (u64)pr0 | ((u64)(u32)__shfl_xor((int)pr0, 2) << 32);
      u64 e1 = (u64)pr1 | ((u64)(u32)__shfl_xor((int)pr1, 2) << 32);
      const int u = colw0 + m16;
      if ((m16 & 3) == 0){
        u64* exw = ex + ((size_t)((t + 1) & 1) * 8 + r0) * 512;
        const int p = (colw0 + m16) >> 2;
        __hip_atomic_store(&exw[p],       e0, AG);
        __hip_atomic_store(&exw[512 + p], e1, AG);
      }
      float pw0 = (u & 1) ? nv0 : nv0 * nv0;       // PowerIndex: even u squared
      float pw1 = (u & 1) ? nv1 : nv1 * nv1;
      out[((size_t)r0 * 1024 + t) * 2176 + 128 + u] = pw0;
      out[((size_t)(r0 + 1) * 1024 + t) * 2176 + 128 + u] = pw1;
    }
  }
}

extern "C" void kernel_launch(void* const* d_in, const int* in_sizes, int n_in,
                              void* d_out, int out_size, void* d_ws, size_t ws_size,
                              hipStream_t stream){
  const float* inputs = (const float*)d_in[0];   // [8,1024,128]
  const float* w_in   = (const float*)d_in[1];   // [128,2048]
  const float* b_in   = (const float*)d_in[2];   // [2048]
  const float* w_res  = (const float*)d_in[3];   // [2048,2048]
  float* out = (float*)d_out;

  u64* ex = (u64*)d_ws;                                         // 2*8*512*8 = 65536 B
  unsigned short* Bsw = (unsigned short*)((char*)d_ws + 65536); // 8,912,896 B swizzled weights

  exinit_kernel<<<32, 256, 0, stream>>>(ex);
  bswz_kernel<<<2176, 256, 0, stream>>>(w_res, w_in, Bsw);
  copy_in_kernel<<<1024, 256, 0, stream>>>(inputs, out);
  esn_persist<<<128, 512, 0, stream>>>(inputs, b_in, Bsw, ex, out);
}